// Round 6
// baseline (762.108 us; speedup 1.0000x reference)
//
#include <hip/hip_runtime.h>
#include <hip/hip_bf16.h>
#include <cstdint>
#include <cstddef>

// Problem: B=128, S=512, H=512, D=1024
// Outputs (flat in d_out): context (128*1024) | aw (128*512) | new_coverage (128*512)

typedef __attribute__((ext_vector_type(8))) short bf16x8;
typedef __attribute__((ext_vector_type(4))) float f32x4;

#define GLOBAL_AS(p) ((const __attribute__((address_space(1))) unsigned int*)(p))
#define LDS_AS(p)    ((__attribute__((address_space(3))) unsigned int*)(p))

__device__ __forceinline__ short f2bf(float f) {
    union { float f; uint32_t u; } v; v.f = f;
    uint32_t u = v.u + 0x7fffu + ((v.u >> 16) & 1u);  // RNE
    return (short)(u >> 16);
}

__device__ __forceinline__ bf16x8 cvt8(float4 a, float4 b) {
    bf16x8 r;
    r[0] = f2bf(a.x); r[1] = f2bf(a.y); r[2] = f2bf(a.z); r[3] = f2bf(a.w);
    r[4] = f2bf(b.x); r[5] = f2bf(b.y); r[6] = f2bf(b.z); r[7] = f2bf(b.w);
    return r;
}

__device__ __forceinline__ float fast_tanh(float x) {
    x = fminf(10.f, fmaxf(-10.f, x));
    float e = __expf(2.f * x);
    return (e - 1.f) / (e + 1.f);
}

// ---------------- prep: Wh fp32->bf16 (blocks 0..1023) + dec split-K GEMM ------
__global__ __launch_bounds__(256) void prep_kernel(
    const float* __restrict__ Wh, short* __restrict__ Wh_bf,
    const float* __restrict__ hd, const float* __restrict__ cd,
    const float* __restrict__ Ws, float* __restrict__ dec_part)
{
    __shared__ __align__(16) short As[128 * 40];
    __shared__ __align__(16) short Bs[128 * 40];
    const int t = threadIdx.x;

    if (blockIdx.x < 1024) {
        int i = blockIdx.x * 1024 + t * 4;
        float4 f = *(const float4*)(Wh + i);
        short4 o;
        o.x = f2bf(f.x); o.y = f2bf(f.y); o.z = f2bf(f.z); o.w = f2bf(f.w);
        *(short4*)(Wh_bf + i) = o;
        return;
    }

    // ---- dec GEMM: M=128, N=1024, K split 4x256 ----
    const int bid = blockIdx.x - 1024;
    const int bx = bid & 7;        // n-tile 0..7
    const int kc = bid >> 3;       // k-chunk 0..3
    const int wv = t >> 6, lane = t & 63, q = lane >> 4, c = lane & 15;
    const int wm = wv & 1, wn = wv >> 1;
    const int ar = t >> 1, ah = t & 1;

    const float* abase = ((kc < 2) ? hd : cd) + (size_t)ar * 512 + (kc & 1) * 256 + ah * 16;
    const float* bbase = Ws + ((size_t)(bx * 128 + ar)) * 1024 + kc * 256 + ah * 16;
    short* awr = &As[ar * 40 + ah * 16];
    short* bwr = &Bs[ar * 40 + ah * 16];

    f32x4 acc[4][4];
#pragma unroll
    for (int i = 0; i < 4; ++i)
#pragma unroll
        for (int j = 0; j < 4; ++j) acc[i][j] = (f32x4){0.f, 0.f, 0.f, 0.f};

    for (int k0 = 0; k0 < 256; k0 += 32) {
        const float4* ap = (const float4*)(abase + k0);
        const float4* bp = (const float4*)(bbase + k0);
        float4 a0 = ap[0], a1 = ap[1], a2 = ap[2], a3 = ap[3];
        float4 b0 = bp[0], b1 = bp[1], b2 = bp[2], b3 = bp[3];
        *(bf16x8*)awr = cvt8(a0, a1);
        *(bf16x8*)(awr + 8) = cvt8(a2, a3);
        *(bf16x8*)bwr = cvt8(b0, b1);
        *(bf16x8*)(bwr + 8) = cvt8(b2, b3);
        __syncthreads();
        bf16x8 af[4], bf[4];
#pragma unroll
        for (int i = 0; i < 4; ++i) af[i] = *(const bf16x8*)&As[(wm * 64 + i * 16 + c) * 40 + q * 8];
#pragma unroll
        for (int j = 0; j < 4; ++j) bf[j] = *(const bf16x8*)&Bs[(wn * 64 + j * 16 + c) * 40 + q * 8];
#pragma unroll
        for (int i = 0; i < 4; ++i)
#pragma unroll
            for (int j = 0; j < 4; ++j)
                acc[i][j] = __builtin_amdgcn_mfma_f32_16x16x32_bf16(af[i], bf[j], acc[i][j], 0, 0, 0);
        __syncthreads();
    }

    const int n0 = bx * 128 + wn * 64;
    float* dp = dec_part + (size_t)kc * 131072;
#pragma unroll
    for (int i = 0; i < 4; ++i)
#pragma unroll
        for (int rr = 0; rr < 4; ++rr) {
            int bidx = wm * 64 + i * 16 + q * 4 + rr;
#pragma unroll
            for (int j = 0; j < 4; ++j)
                dp[(size_t)bidx * 1024 + n0 + j * 16 + c] = acc[i][j][rr];
        }
}

// ---------------- main score GEMM: fp32-A reg-staged pipeline ------------------
// M=65536, N=1024, K=1024. 128x128 tile, dbuf LDS (32 KB). A: global fp32 ->
// regs (1 iter of slack) -> cvt -> swizzled ds_write into next buffer. B: bf16
// DMA (L2-hot, issued after A loads so reg-dependency waits leave it in
// flight). Barrier drain only covers B-DMA + ds_write. XCD-affine grid.
__global__ __launch_bounds__(256) void attn_score_gemm6(
    const float* __restrict__ enc, const short* __restrict__ Whb,
    const float* __restrict__ dec_part, const float* __restrict__ Wsb,
    const float* __restrict__ cov,
    const float* __restrict__ wc_w, const float* __restrict__ v_w,
    float* __restrict__ p_part)
{
    __shared__ __align__(16) short As[2][128 * 32];  // 8 KB per buf
    __shared__ __align__(16) short Bs[2][128 * 32];
    const int t = threadIdx.x;
    const int lin = blockIdx.x;
    const int xcd = lin & 7;
    const int kk  = lin >> 3;
    const int bx  = kk & 7;                    // n-tile (fast within XCD -> L2 A reuse)
    const int by  = xcd * 64 + (kk >> 3);      // m-tile 0..511
    const int b   = by >> 2;
    const int s0  = (by & 3) * 128;

    const int wv = t >> 6, lane = t & 63, q = lane >> 4, c = lane & 15;
    const int wm = wv & 1, wn = wv >> 1;

    // ---- A staging (registers): thread covers row ar, cols [ah*16, ah*16+16)
    const int ar = t & 127;
    const int ah = t >> 7;
    const int sA = (ar ^ (ar >> 2)) & 3;       // XOR swizzle for this row
    const float* aptr = enc + ((size_t)(by * 128 + ar)) * 1024 + ah * 16;
    const int awoff0 = ar * 32 + (((ah * 2) ^ sA)) * 8;
    const int awoff1 = ar * 32 + (((ah * 2 + 1) ^ sA)) * 8;

    // ---- B staging (DMA): lane l -> row wv*16 + l/4, slot l&3, swizzled source
    const int srow = wv * 16 + (lane >> 2);
    const int gg = (lane & 3) ^ ((srow ^ (srow >> 2)) & 3);
    const short* bg0 = Whb + ((size_t)(bx * 128 + srow)) * 1024 + gg * 8;
    const short* bg1 = bg0 + (size_t)64 * 1024;
    const int loB0 = wv * 512;
    const int loB1 = 2048 + wv * 512;

    // fragment-read swizzle (fragment row ≡ c mod 16)
    const int qa = (q ^ ((c ^ (c >> 2)) & 3)) * 8;

    f32x4 acc[4][4];
#pragma unroll
    for (int i = 0; i < 4; ++i)
#pragma unroll
        for (int j = 0; j < 4; ++j) acc[i][j] = (f32x4){0.f, 0.f, 0.f, 0.f};

    // prologue: stage k-tile 0
    {
        const float4* ap = (const float4*)aptr;
        float4 f0 = ap[0], f1 = ap[1], f2 = ap[2], f3 = ap[3];
        __builtin_amdgcn_global_load_lds(GLOBAL_AS(bg0), LDS_AS(&Bs[0][loB0]), 16, 0, 0);
        __builtin_amdgcn_global_load_lds(GLOBAL_AS(bg1), LDS_AS(&Bs[0][loB1]), 16, 0, 0);
        *(bf16x8*)&As[0][awoff0] = cvt8(f0, f1);
        *(bf16x8*)&As[0][awoff1] = cvt8(f2, f3);
        __syncthreads();
    }

    for (int k0 = 0; k0 < 32; ++k0) {
        const int cur = k0 & 1;
        const int nxt = cur ^ 1;
        float4 f0, f1, f2, f3;
        if (k0 < 31) {
            const int kb = (k0 + 1) * 32;
            const float4* ap = (const float4*)(aptr + kb);
            f0 = ap[0]; f1 = ap[1]; f2 = ap[2]; f3 = ap[3];
            __builtin_amdgcn_global_load_lds(GLOBAL_AS(bg0 + kb), LDS_AS(&Bs[nxt][loB0]), 16, 0, 0);
            __builtin_amdgcn_global_load_lds(GLOBAL_AS(bg1 + kb), LDS_AS(&Bs[nxt][loB1]), 16, 0, 0);
        }
        bf16x8 af[4], bf[4];
#pragma unroll
        for (int i = 0; i < 4; ++i) af[i] = *(const bf16x8*)&As[cur][(wm * 64 + i * 16 + c) * 32 + qa];
#pragma unroll
        for (int j = 0; j < 4; ++j) bf[j] = *(const bf16x8*)&Bs[cur][(wn * 64 + j * 16 + c) * 32 + qa];
#pragma unroll
        for (int i = 0; i < 4; ++i)
#pragma unroll
            for (int j = 0; j < 4; ++j)
                acc[i][j] = __builtin_amdgcn_mfma_f32_16x16x32_bf16(af[i], bf[j], acc[i][j], 0, 0, 0);
        if (k0 < 31) {
            *(bf16x8*)&As[nxt][awoff0] = cvt8(f0, f1);
            *(bf16x8*)&As[nxt][awoff1] = cvt8(f2, f3);
        }
        __syncthreads();
    }

    // Epilogue: p = sum_e v[e]*tanh(acc + dec[b,e] + cov[b,s]*wc[e])
    const int n0 = bx * 128 + wn * 64;
    float v_e[4], wc_e[4], dec_e[4];
#pragma unroll
    for (int j = 0; j < 4; ++j) {
        int e = n0 + j * 16 + c;
        v_e[j]  = v_w[e];
        wc_e[j] = wc_w[e];
        float d = Wsb[e];
#pragma unroll
        for (int p = 0; p < 4; ++p) d += dec_part[(size_t)p * 131072 + (size_t)b * 1024 + e];
        dec_e[j] = d;
    }
    const float* covb = cov + (size_t)b * 512;
    float* pp = p_part + ((size_t)(bx * 2 + wn)) * 65536 + (size_t)b * 512;
#pragma unroll
    for (int i = 0; i < 4; ++i)
#pragma unroll
        for (int rr = 0; rr < 4; ++rr) {
            int s = s0 + wm * 64 + i * 16 + q * 4 + rr;
            float cs = covb[s];
            float p = 0.f;
#pragma unroll
            for (int j = 0; j < 4; ++j) {
                float att = acc[i][j][rr] + dec_e[j] + cs * wc_e[j];
                p += v_e[j] * fast_tanh(att);
            }
            p += __shfl_xor(p, 1);
            p += __shfl_xor(p, 2);
            p += __shfl_xor(p, 4);
            p += __shfl_xor(p, 8);
            if (c == 0) pp[s] = p;
        }
}

// ---------------- softmax: sum 16 partials, masked softmax + renorm ------------
__global__ __launch_bounds__(512) void softmax_kernel(
    const float* __restrict__ p_part, const float* __restrict__ mask,
    const float* __restrict__ cov, float* __restrict__ aw, float* __restrict__ ncov)
{
    __shared__ float red[8];
    const int b = blockIdx.x, t = threadIdx.x;
    const int w = t >> 6, lane = t & 63;
    const size_t idx = (size_t)b * 512 + t;

    float sc = 0.f;
#pragma unroll
    for (int k = 0; k < 16; ++k) sc += p_part[(size_t)k * 65536 + idx];

    float m = sc;
#pragma unroll
    for (int o = 1; o < 64; o <<= 1) m = fmaxf(m, __shfl_xor(m, o));
    if (lane == 0) red[w] = m;
    __syncthreads();
#pragma unroll
    for (int i = 0; i < 8; ++i) m = fmaxf(m, red[i]);
    __syncthreads();

    float e = __expf(sc - m);
    float s = e;
#pragma unroll
    for (int o = 1; o < 64; o <<= 1) s += __shfl_xor(s, o);
    if (lane == 0) red[w] = s;
    __syncthreads();
    s = 0.f;
#pragma unroll
    for (int i = 0; i < 8; ++i) s += red[i];
    __syncthreads();

    float wv = (e / s) * mask[idx];
    float s2 = wv;
#pragma unroll
    for (int o = 1; o < 64; o <<= 1) s2 += __shfl_xor(s2, o);
    if (lane == 0) red[w] = s2;
    __syncthreads();
    s2 = 0.f;
#pragma unroll
    for (int i = 0; i < 8; ++i) s2 += red[i];

    float awv = wv / s2;
    aw[idx] = awv;
    ncov[idx] = cov[idx] + awv;
}

// ---------------- context: fp32 enc, partial sums (no atomics) + reduce --------
// cpart[16][128][1024]: slice = s-chunk of 32
__global__ __launch_bounds__(256) void context_f32_part(
    const float* __restrict__ enc, const float* __restrict__ aw, float* __restrict__ cpart)
{
    const int sc = blockIdx.x & 15;    // 16 s-chunks of 32
    const int b  = blockIdx.x >> 4;    // 0..127
    const int t  = threadIdx.x;        // float4 per thread covers D=1024
    const float* ebase = enc + ((size_t)(b * 512 + sc * 32)) * 1024 + t * 4;
    const float* awp = aw + (size_t)b * 512 + sc * 32;
    float ax = 0.f, ay = 0.f, az = 0.f, aww = 0.f;
#pragma unroll 8
    for (int s = 0; s < 32; ++s) {
        float w = awp[s];
        float4 e4 = *(const float4*)(ebase + (size_t)s * 1024);
        ax += w * e4.x; ay += w * e4.y; az += w * e4.z; aww += w * e4.w;
    }
    float* cp = cpart + ((size_t)(sc * 128 + b)) * 1024 + t * 4;
    *(float4*)cp = (float4){ax, ay, az, aww};
}

__global__ __launch_bounds__(256) void ctx_reduce(
    const float* __restrict__ cpart, float* __restrict__ ctx)
{
    int i = blockIdx.x * 256 + threadIdx.x;   // 131072 outputs
    float s = 0.f;
#pragma unroll
    for (int k = 0; k < 16; ++k) s += cpart[(size_t)k * 131072 + i];
    ctx[i] = s;
}

extern "C" void kernel_launch(void* const* d_in, const int* in_sizes, int n_in,
                              void* d_out, int out_size, void* d_ws, size_t ws_size,
                              hipStream_t stream) {
    const float* hd   = (const float*)d_in[0];
    const float* cd   = (const float*)d_in[1];
    const float* enc  = (const float*)d_in[2];
    const float* mask = (const float*)d_in[3];
    const float* cov  = (const float*)d_in[4];
    const float* Wh   = (const float*)d_in[5];
    const float* Ws   = (const float*)d_in[6];
    const float* Wsb  = (const float*)d_in[7];
    const float* vw   = (const float*)d_in[8];
    const float* wcw  = (const float*)d_in[9];

    float* out  = (float*)d_out;
    float* ctx  = out;
    float* aw   = out + 131072;
    float* ncov = out + 196608;

    // ws layout: p_part 4MB @0 | dec_part 2MB @4M | Wh_bf 2MB @6M | cpart 8MB @8M = 16MB
    char* ws = (char*)d_ws;
    float* p_part   = (float*)ws;
    float* dec_part = (float*)(ws + (4u << 20));
    short* Wh_bf    = (short*)(ws + (6u << 20));
    float* cpart    = (float*)(ws + (8u << 20));

    prep_kernel<<<1056, 256, 0, stream>>>(Wh, Wh_bf, hd, cd, Ws, dec_part);
    attn_score_gemm6<<<4096, 256, 0, stream>>>(enc, Wh_bf, dec_part, Wsb, cov, wcw, vw, p_part);
    softmax_kernel<<<128, 512, 0, stream>>>(p_part, mask, cov, aw, ncov);
    context_f32_part<<<2048, 256, 0, stream>>>(enc, aw, cpart);
    ctx_reduce<<<512, 256, 0, stream>>>(cpart, ctx);
}